// Round 2
// baseline (6821.568 us; speedup 1.0000x reference)
//
#include <hip/hip_runtime.h>
#include <hip/hip_bf16.h>
#include <math.h>

#define C_DIM   384
#define T_SEQ   128
#define B_SZ    64
#define H_HEADS 6
#define DH      64
#define L_LAYERS 6
#define FF_DIM  1536
#define V_DIM   25000
#define NTOK    8192   // B*T

// ---------------- embedding: x = tok_emb[idx] + pos_emb[t] ----------------
__global__ __launch_bounds__(256) void embed_kernel(
    const int* __restrict__ idx, const float* __restrict__ tok,
    const float* __restrict__ pos, float* __restrict__ x)
{
    int e = blockIdx.x * 256 + threadIdx.x;
    if (e >= NTOK * C_DIM) return;
    int bt = e / C_DIM, c = e - bt * C_DIM;
    int t = bt % T_SEQ;
    x[e] = tok[(size_t)idx[bt] * C_DIM + c] + pos[t * C_DIM + c];
}

// ---------------- layernorm: one wave (64 threads) per row ----------------
__global__ __launch_bounds__(64) void ln_kernel(
    const float* __restrict__ x, const float* __restrict__ g,
    const float* __restrict__ b, float* __restrict__ out)
{
    int row = blockIdx.x, lane = threadIdx.x;
    const float* xr = x + (size_t)row * C_DIM;
    float v[6];
    float s = 0.f;
#pragma unroll
    for (int i = 0; i < 6; ++i) { v[i] = xr[lane + i * 64]; s += v[i]; }
#pragma unroll
    for (int o = 32; o > 0; o >>= 1) s += __shfl_xor(s, o);
    float mu = s * (1.f / 384.f);
    float var = 0.f;
#pragma unroll
    for (int i = 0; i < 6; ++i) { float d = v[i] - mu; var += d * d; }
#pragma unroll
    for (int o = 32; o > 0; o >>= 1) var += __shfl_xor(var, o);
    float rs = rsqrtf(var * (1.f / 384.f) + 1e-5f);
    float* orow = out + (size_t)row * C_DIM;
#pragma unroll
    for (int i = 0; i < 6; ++i) {
        int c = lane + i * 64;
        orow[c] = (v[i] - mu) * rs * g[c] + b[c];
    }
}

// ---------------- fp32 SGEMM: C = A[M,K] @ B[K,N] (+bias)(relu)(+resid) ---
// BM=128, BN=64, BK=16, 256 threads, 8x4 micro-tile.
#define BM 128
#define BN 64
#define BK 16
__global__ __launch_bounds__(256) void sgemm_kernel(
    const float* __restrict__ A, const float* __restrict__ B,
    const float* __restrict__ bias, const float* __restrict__ resid,
    float* __restrict__ Cmat, int M, int N, int K, int relu)
{
    __shared__ float As[BK][BM];   // transposed A tile: As[k][m]
    __shared__ float Bs[BK][BN];   // Bs[k][n]
    int tid = threadIdx.x;
    int m0 = blockIdx.y * BM;
    int n0 = blockIdx.x * BN;
    int tx = tid & 15;             // 16 cols-groups * TN=4 -> 64
    int ty = tid >> 4;             // 16 row-groups * TM=8 -> 128

    float acc[8][4];
#pragma unroll
    for (int i = 0; i < 8; ++i)
#pragma unroll
        for (int j = 0; j < 4; ++j) acc[i][j] = 0.f;

    for (int k0 = 0; k0 < K; k0 += BK) {
        // load A tile: 128x16 floats = 512 float4, 2 per thread; transpose into As
#pragma unroll
        for (int it = 0; it < 2; ++it) {
            int f4 = tid + it * 256;
            int m = f4 >> 2, kq = f4 & 3;
            const float4 av = *reinterpret_cast<const float4*>(
                &A[(size_t)(m0 + m) * K + k0 + kq * 4]);
            As[kq * 4 + 0][m] = av.x;
            As[kq * 4 + 1][m] = av.y;
            As[kq * 4 + 2][m] = av.z;
            As[kq * 4 + 3][m] = av.w;
        }
        // load B tile: 16x64 floats = 256 float4, 1 per thread
        {
            int kk = tid >> 4, nq = tid & 15;
            int n = n0 + nq * 4;
            float4 bv;
            const float* brow = &B[(size_t)(k0 + kk) * N];
            if (n + 3 < N) {
                bv = *reinterpret_cast<const float4*>(&brow[n]);
            } else {
                bv.x = (n + 0 < N) ? brow[n + 0] : 0.f;
                bv.y = (n + 1 < N) ? brow[n + 1] : 0.f;
                bv.z = (n + 2 < N) ? brow[n + 2] : 0.f;
                bv.w = (n + 3 < N) ? brow[n + 3] : 0.f;
            }
            *reinterpret_cast<float4*>(&Bs[kk][nq * 4]) = bv;
        }
        __syncthreads();
#pragma unroll
        for (int kk = 0; kk < BK; ++kk) {
            float4 a01 = *reinterpret_cast<const float4*>(&As[kk][ty * 8]);
            float4 a23 = *reinterpret_cast<const float4*>(&As[kk][ty * 8 + 4]);
            float4 bb  = *reinterpret_cast<const float4*>(&Bs[kk][tx * 4]);
            float av[8] = {a01.x, a01.y, a01.z, a01.w, a23.x, a23.y, a23.z, a23.w};
            float bv[4] = {bb.x, bb.y, bb.z, bb.w};
#pragma unroll
            for (int i = 0; i < 8; ++i)
#pragma unroll
                for (int j = 0; j < 4; ++j)
                    acc[i][j] = fmaf(av[i], bv[j], acc[i][j]);
        }
        __syncthreads();
    }
    // epilogue
#pragma unroll
    for (int i = 0; i < 8; ++i) {
        int m = m0 + ty * 8 + i;
#pragma unroll
        for (int j = 0; j < 4; ++j) {
            int n = n0 + tx * 4 + j;
            if (n < N) {
                float v = acc[i][j];
                if (bias) v += bias[n];
                if (relu) v = fmaxf(v, 0.f);
                if (resid) v += resid[(size_t)m * N + n];
                Cmat[(size_t)m * N + n] = v;
            }
        }
    }
}

// ---------------- fused causal attention: one block per (b,h) -------------
// 128 threads = one row each; K,V in LDS (64KB), q-row + o in registers.
__global__ __launch_bounds__(128) void attn_kernel(
    const float* __restrict__ Q, const float* __restrict__ K,
    const float* __restrict__ Vv, float* __restrict__ O)
{
    __shared__ float ks[T_SEQ * DH];
    __shared__ float vs[T_SEQ * DH];
    int bh = blockIdx.x;
    int b = bh / H_HEADS, h = bh - b * H_HEADS;
    int tid = threadIdx.x;  // row
    size_t base = ((size_t)b * T_SEQ) * C_DIM + h * DH;

    for (int e = tid; e < T_SEQ * DH; e += 128) {
        int row = e >> 6, d = e & 63;
        ks[e] = K[base + (size_t)row * C_DIM + d];
        vs[e] = Vv[base + (size_t)row * C_DIM + d];
    }
    float qr[DH];
    const float* qp = Q + base + (size_t)tid * C_DIM;
#pragma unroll
    for (int d = 0; d < DH; ++d) qr[d] = qp[d] * 0.125f;  // 1/sqrt(64) folded
    __syncthreads();

    int r = tid;
    // pass 1: online max + sum
    float m = -1e30f, lsum = 0.f;
    for (int s = 0; s <= r; ++s) {
        float dot = 0.f;
#pragma unroll
        for (int d = 0; d < DH; ++d) dot = fmaf(qr[d], ks[s * DH + d], dot);
        float mn = fmaxf(m, dot);
        lsum = lsum * expf(m - mn) + expf(dot - mn);
        m = mn;
    }
    float inv = 1.f / lsum;
    float o[DH];
#pragma unroll
    for (int d = 0; d < DH; ++d) o[d] = 0.f;
    // pass 2: accumulate P @ V
    for (int s = 0; s <= r; ++s) {
        float dot = 0.f;
#pragma unroll
        for (int d = 0; d < DH; ++d) dot = fmaf(qr[d], ks[s * DH + d], dot);
        float p = expf(dot - m) * inv;
#pragma unroll
        for (int d = 0; d < DH; ++d) o[d] = fmaf(p, vs[s * DH + d], o[d]);
    }
    __syncthreads();
#pragma unroll
    for (int d = 0; d < DH; ++d) ks[r * DH + d] = o[d];
    __syncthreads();
    for (int e = tid; e < T_SEQ * DH; e += 128) {
        int row = e >> 6, d = e & 63;
        O[base + (size_t)row * C_DIM + d] = ks[e];
    }
}

// ---------------- loss: per-row logsumexp + NLL ---------------------------
__global__ __launch_bounds__(256) void loss_row_kernel(
    const float* __restrict__ logits, const int* __restrict__ tgt,
    float* __restrict__ nll)
{
    __shared__ float red[4];
    int row = blockIdx.x;
    const float* lr = logits + (size_t)row * V_DIM;
    float m = -1e30f;
    for (int i = threadIdx.x; i < V_DIM; i += 256) m = fmaxf(m, lr[i]);
#pragma unroll
    for (int o = 32; o > 0; o >>= 1) m = fmaxf(m, __shfl_xor(m, o));
    if ((threadIdx.x & 63) == 0) red[threadIdx.x >> 6] = m;
    __syncthreads();
    m = fmaxf(fmaxf(red[0], red[1]), fmaxf(red[2], red[3]));
    __syncthreads();

    float s = 0.f;
    for (int i = threadIdx.x; i < V_DIM; i += 256) s += expf(lr[i] - m);
#pragma unroll
    for (int o = 32; o > 0; o >>= 1) s += __shfl_xor(s, o);
    if ((threadIdx.x & 63) == 0) red[threadIdx.x >> 6] = s;
    __syncthreads();
    s = red[0] + red[1] + red[2] + red[3];

    if (threadIdx.x == 0) nll[row] = -(lr[tgt[row]] - m - logf(s));
}

__global__ __launch_bounds__(256) void loss_final_kernel(
    const float* __restrict__ nll, float* __restrict__ out)
{
    __shared__ float red[4];
    float s = 0.f;
    for (int i = threadIdx.x; i < NTOK; i += 256) s += nll[i];
#pragma unroll
    for (int o = 32; o > 0; o >>= 1) s += __shfl_xor(s, o);
    if ((threadIdx.x & 63) == 0) red[threadIdx.x >> 6] = s;
    __syncthreads();
    if (threadIdx.x == 0)
        out[0] = (red[0] + red[1] + red[2] + red[3]) * (1.f / NTOK);
}

// ---------------- host launch --------------------------------------------
extern "C" void kernel_launch(void* const* d_in, const int* in_sizes, int n_in,
                              void* d_out, int out_size, void* d_ws, size_t ws_size,
                              hipStream_t stream)
{
    const int*   idx     = (const int*)d_in[0];
    const int*   targets = (const int*)d_in[1];
    const float* tok_emb = (const float*)d_in[2];
    const float* pos_emb = (const float*)d_in[3];
    const float* wq      = (const float*)d_in[4];
    const float* wk      = (const float*)d_in[5];
    const float* wv      = (const float*)d_in[6];
    const float* wo      = (const float*)d_in[7];
    const float* bo      = (const float*)d_in[8];
    const float* ln1_g   = (const float*)d_in[9];
    const float* ln1_b   = (const float*)d_in[10];
    const float* ln2_g   = (const float*)d_in[11];
    const float* ln2_b   = (const float*)d_in[12];
    const float* w1      = (const float*)d_in[13];
    const float* b1      = (const float*)d_in[14];
    const float* w2      = (const float*)d_in[15];
    const float* b2      = (const float*)d_in[16];
    const float* lnf_g   = (const float*)d_in[17];
    const float* lnf_b   = (const float*)d_in[18];
    const float* lm_w    = (const float*)d_in[19];
    const float* lm_b    = (const float*)d_in[20];
    float* out = (float*)d_out;

    const size_t XC = (size_t)NTOK * C_DIM;      // 3,145,728
    // persistent-ish scratch in ws: x, h, nll (~25 MB)
    float* x    = (float*)d_ws;
    float* hbuf = x + XC;
    float* nll  = hbuf + XC;
    // transient scratch carved from d_out's logits region (dead before the
    // final logits GEMM overwrites it): q, k, v, ff  (~21.2M floats << 204.8M)
    float* q  = out;
    float* k  = q + XC;
    float* v  = k + XC;
    float* ff = v + XC;                          // NTOK*FF_DIM = 12.6M floats

    dim3 blk256(256), blk128(128), blk64(64);

    // embedding
    embed_kernel<<<(NTOK * C_DIM + 255) / 256, blk256, 0, stream>>>(
        idx, tok_emb, pos_emb, x);

    dim3 gC((C_DIM + BN - 1) / BN, NTOK / BM);   // 6 x 64
    dim3 gF((FF_DIM + BN - 1) / BN, NTOK / BM);  // 24 x 64
    dim3 gV((V_DIM + BN - 1) / BN, NTOK / BM);   // 391 x 64

    for (int l = 0; l < L_LAYERS; ++l) {
        const float* wq_l = wq + (size_t)l * C_DIM * C_DIM;
        const float* wk_l = wk + (size_t)l * C_DIM * C_DIM;
        const float* wv_l = wv + (size_t)l * C_DIM * C_DIM;
        const float* wo_l = wo + (size_t)l * C_DIM * C_DIM;
        const float* w1_l = w1 + (size_t)l * C_DIM * FF_DIM;
        const float* w2_l = w2 + (size_t)l * FF_DIM * C_DIM;

        ln_kernel<<<NTOK, blk64, 0, stream>>>(x, ln1_g + l * C_DIM, ln1_b + l * C_DIM, hbuf);
        sgemm_kernel<<<gC, blk256, 0, stream>>>(hbuf, wq_l, nullptr, nullptr, q,
                                                NTOK, C_DIM, C_DIM, 0);
        sgemm_kernel<<<gC, blk256, 0, stream>>>(hbuf, wk_l, nullptr, nullptr, k,
                                                NTOK, C_DIM, C_DIM, 0);
        sgemm_kernel<<<gC, blk256, 0, stream>>>(hbuf, wv_l, nullptr, nullptr, v,
                                                NTOK, C_DIM, C_DIM, 0);
        attn_kernel<<<B_SZ * H_HEADS, blk128, 0, stream>>>(q, k, v, hbuf);
        sgemm_kernel<<<gC, blk256, 0, stream>>>(hbuf, wo_l, bo + l * C_DIM, x, x,
                                                NTOK, C_DIM, C_DIM, 0);
        ln_kernel<<<NTOK, blk64, 0, stream>>>(x, ln2_g + l * C_DIM, ln2_b + l * C_DIM, hbuf);
        sgemm_kernel<<<gF, blk256, 0, stream>>>(hbuf, w1_l, b1 + l * FF_DIM, nullptr, ff,
                                                NTOK, FF_DIM, C_DIM, 1);
        sgemm_kernel<<<gC, blk256, 0, stream>>>(ff, w2_l, b2 + l * C_DIM, x, x,
                                                NTOK, C_DIM, FF_DIM, 0);
    }

    // final LN + logits
    ln_kernel<<<NTOK, blk64, 0, stream>>>(x, lnf_g, lnf_b, hbuf);
    sgemm_kernel<<<gV, blk256, 0, stream>>>(hbuf, lm_w, lm_b, nullptr, out,
                                            NTOK, V_DIM, C_DIM, 0);

    // loss
    loss_row_kernel<<<NTOK, blk256, 0, stream>>>(out, targets, nll);
    loss_final_kernel<<<1, blk256, 0, stream>>>(nll, out + (size_t)NTOK * V_DIM);
}

// Round 4
// 3682.454 us; speedup vs baseline: 1.8525x; 1.8525x over previous
//
#include <hip/hip_runtime.h>
#include <hip/hip_bf16.h>
#include <math.h>

#define C_DIM   384
#define T_SEQ   128
#define B_SZ    64
#define H_HEADS 6
#define DH      64
#define L_LAYERS 6
#define FF_DIM  1536
#define V_DIM   25000
#define V_PAD   25088
#define NTOK    8192   // B*T
#define QKV_LD  1152   // 3*C

typedef __hip_bfloat16 bf16;
using f32x4 = __attribute__((ext_vector_type(4))) float;
using s16x8 = __attribute__((ext_vector_type(8))) short;

#define GLOBAL_LOAD_LDS16(gptr, lptr)                                          \
    __builtin_amdgcn_global_load_lds(                                          \
        (const __attribute__((address_space(1))) void*)(gptr),                 \
        (__attribute__((address_space(3))) void*)(lptr), 16, 0, 0)

// ---------------- embedding: x = tok_emb[idx] + pos_emb[t] ----------------
__global__ __launch_bounds__(256) void embed_kernel(
    const int* __restrict__ idx, const float* __restrict__ tok,
    const float* __restrict__ pos, float* __restrict__ x)
{
    int e = blockIdx.x * 256 + threadIdx.x;
    if (e >= NTOK * C_DIM) return;
    int bt = e / C_DIM, c = e - bt * C_DIM;
    int t = bt % T_SEQ;
    x[e] = tok[(size_t)idx[bt] * C_DIM + c] + pos[t * C_DIM + c];
}

// ---------------- layernorm: one wave per row, bf16 out -------------------
__global__ __launch_bounds__(64) void ln_kernel(
    const float* __restrict__ x, const float* __restrict__ g,
    const float* __restrict__ b, bf16* __restrict__ out)
{
    int row = blockIdx.x, lane = threadIdx.x;
    const float* xr = x + (size_t)row * C_DIM;
    float v[6];
    float s = 0.f;
#pragma unroll
    for (int i = 0; i < 6; ++i) { v[i] = xr[lane + i * 64]; s += v[i]; }
#pragma unroll
    for (int o = 32; o > 0; o >>= 1) s += __shfl_xor(s, o);
    float mu = s * (1.f / 384.f);
    float var = 0.f;
#pragma unroll
    for (int i = 0; i < 6; ++i) { float d = v[i] - mu; var += d * d; }
#pragma unroll
    for (int o = 32; o > 0; o >>= 1) var += __shfl_xor(var, o);
    float rs = rsqrtf(var * (1.f / 384.f) + 1e-5f);
    bf16* orow = out + (size_t)row * C_DIM;
#pragma unroll
    for (int i = 0; i < 6; ++i) {
        int c = lane + i * 64;
        orow[c] = __float2bfloat16((v[i] - mu) * rs * g[c] + b[c]);
    }
}

// ---------------- transpose + fp32->bf16 weight convert -------------------
// in_z = in + z*in_stride, shape [K][N] row-major (fp32)
// out_z = out + z*out_stride; out_z[(row_off + n)*out_ld + k] = in_z[k][n]
// rows n in [N, Npad) get zeros.
__global__ __launch_bounds__(256) void tcvt_kernel(
    const float* __restrict__ in, bf16* __restrict__ out,
    int K, int N, int Npad, long long in_stride, long long out_stride,
    int row_off, int out_ld)
{
    __shared__ float t[32][33];
    int z = blockIdx.z;
    const float* inz = in + (size_t)z * in_stride;
    bf16* outz = out + (size_t)z * out_stride;
    int n0 = blockIdx.x * 32, k0 = blockIdx.y * 32;
    int tx = threadIdx.x, ty = threadIdx.y;   // block (32,8)
    for (int a = ty; a < 32; a += 8) {
        int k = k0 + a, n = n0 + tx;
        t[a][tx] = (k < K && n < N) ? inz[(size_t)k * N + n] : 0.f;
    }
    __syncthreads();
    for (int bq = ty; bq < 32; bq += 8) {
        int n = n0 + bq, k = k0 + tx;
        if (n < Npad && k < K)
            outz[(size_t)(row_off + n) * out_ld + k] = __float2bfloat16(t[tx][bq]);
    }
}

// ---------------- bf16 MFMA GEMM: C = A[M,K] @ BT[N,K]^T ------------------
// 128x128 tile, BK=64, 4 waves, 4x4 16x16x32 fragments per wave.
// A, BT bf16 row-major (ld=K). N may have a tail (stores guarded); staging
// rows of BT must be valid up to gridDim.x*128 (pad weights!).
__global__ __launch_bounds__(256) void bgemm_kernel(
    const bf16* __restrict__ A, const bf16* __restrict__ BT,
    const float* __restrict__ bias, const float* __restrict__ resid,
    void* __restrict__ Cout, int M, int N, int K, int relu, int out_bf16)
{
    __shared__ bf16 As[128 * 64];
    __shared__ bf16 Bs[128 * 64];
    const int tid = threadIdx.x;
    const int wave = tid >> 6, lane = tid & 63;
    const int m0 = blockIdx.y * 128, n0 = blockIdx.x * 128;
    const int wr = wave >> 1, wc = wave & 1;   // 64x64 wave sub-tile

    f32x4 acc[4][4];
#pragma unroll
    for (int i = 0; i < 4; ++i)
#pragma unroll
        for (int j = 0; j < 4; ++j) acc[i][j] = (f32x4){0.f, 0.f, 0.f, 0.f};

    // staging: thread tid covers LDS bytes [tid*16 + i*4096, +16)
    // -> row = tid/8 + i*32, col8 = (tid&7)*8  (tile ld = 64 bf16 = 128 B)
    const int srow = tid >> 3;
    const int scol = (tid & 7) * 8;
    const size_t abase = (size_t)(m0 + srow) * K + scol;
    const size_t bbase = (size_t)(n0 + srow) * K + scol;

    const int a_lrow = wr * 64 + (lane & 15);
    const int b_lrow = wc * 64 + (lane & 15);
    const int l_koff = (lane >> 4) * 8;

    for (int k0 = 0; k0 < K; k0 += 64) {
#pragma unroll
        for (int i = 0; i < 4; ++i) {
            GLOBAL_LOAD_LDS16(A + abase + (size_t)i * 32 * K + k0,
                              As + wave * 512 + i * 2048);
            GLOBAL_LOAD_LDS16(BT + bbase + (size_t)i * 32 * K + k0,
                              Bs + wave * 512 + i * 2048);
        }
        __syncthreads();   // drains vmcnt before ds_read
#pragma unroll
        for (int kk = 0; kk < 2; ++kk) {
            s16x8 a[4], b[4];
#pragma unroll
            for (int mi = 0; mi < 4; ++mi)
                a[mi] = *(const s16x8*)(As + (a_lrow + mi * 16) * 64 + kk * 32 + l_koff);
#pragma unroll
            for (int ni = 0; ni < 4; ++ni)
                b[ni] = *(const s16x8*)(Bs + (b_lrow + ni * 16) * 64 + kk * 32 + l_koff);
#pragma unroll
            for (int mi = 0; mi < 4; ++mi)
#pragma unroll
                for (int ni = 0; ni < 4; ++ni)
                    acc[mi][ni] = __builtin_amdgcn_mfma_f32_16x16x32_bf16(
                        a[mi], b[ni], acc[mi][ni], 0, 0, 0);
        }
        __syncthreads();
    }

    // epilogue: D lane mapping col = lane&15, row = (lane>>4)*4 + r
    const int erow = (lane >> 4) * 4;
    const int ecol = lane & 15;
#pragma unroll
    for (int mi = 0; mi < 4; ++mi) {
#pragma unroll
        for (int ni = 0; ni < 4; ++ni) {
            int n = n0 + wc * 64 + ni * 16 + ecol;
            if (n >= N) continue;
            float bv = bias ? bias[n] : 0.f;
#pragma unroll
            for (int r = 0; r < 4; ++r) {
                int m = m0 + wr * 64 + mi * 16 + erow + r;
                float v = acc[mi][ni][r] + bv;
                if (relu) v = fmaxf(v, 0.f);
                if (resid) v += resid[(size_t)m * N + n];
                if (out_bf16)
                    ((bf16*)Cout)[(size_t)m * N + n] = __float2bfloat16(v);
                else
                    ((float*)Cout)[(size_t)m * N + n] = v;
            }
        }
    }
}

// ---------------- fused causal attention: one block per (b,h) -------------
// QKV fused buffer [NTOK][1152]: q | k | v each C=384 wide. bf16 output.
__global__ __launch_bounds__(128) void attn_kernel(
    const float* __restrict__ QKV, bf16* __restrict__ O)
{
    __shared__ float ks[T_SEQ * DH];
    __shared__ float vs[T_SEQ * DH];
    int bh = blockIdx.x;
    int b = bh / H_HEADS, h = bh - b * H_HEADS;
    int tid = threadIdx.x;  // row
    size_t rowbase = (size_t)b * T_SEQ * QKV_LD;
    int coff = h * DH;

    for (int e = tid; e < T_SEQ * DH; e += 128) {
        int row = e >> 6, d = e & 63;
        ks[e] = QKV[rowbase + (size_t)row * QKV_LD + 384 + coff + d];
        vs[e] = QKV[rowbase + (size_t)row * QKV_LD + 768 + coff + d];
    }
    float qr[DH];
    const float* qp = QKV + rowbase + (size_t)tid * QKV_LD + coff;
#pragma unroll
    for (int d = 0; d < DH; ++d) qr[d] = qp[d] * 0.125f;  // 1/sqrt(64)
    __syncthreads();

    int r = tid;
    float m = -1e30f, lsum = 0.f;
    for (int s = 0; s <= r; ++s) {
        float dot = 0.f;
#pragma unroll
        for (int d = 0; d < DH; ++d) dot = fmaf(qr[d], ks[s * DH + d], dot);
        float mn = fmaxf(m, dot);
        lsum = lsum * expf(m - mn) + expf(dot - mn);
        m = mn;
    }
    float inv = 1.f / lsum;
    float o[DH];
#pragma unroll
    for (int d = 0; d < DH; ++d) o[d] = 0.f;
    for (int s = 0; s <= r; ++s) {
        float dot = 0.f;
#pragma unroll
        for (int d = 0; d < DH; ++d) dot = fmaf(qr[d], ks[s * DH + d], dot);
        float p = expf(dot - m) * inv;
#pragma unroll
        for (int d = 0; d < DH; ++d) o[d] = fmaf(p, vs[s * DH + d], o[d]);
    }
    __syncthreads();
#pragma unroll
    for (int d = 0; d < DH; ++d) ks[r * DH + d] = o[d];
    __syncthreads();
    for (int e = tid; e < T_SEQ * DH; e += 128) {
        int row = e >> 6, d = e & 63;
        O[((size_t)b * T_SEQ + row) * C_DIM + coff + d] = __float2bfloat16(ks[e]);
    }
}

// ---------------- loss: per-row logsumexp + NLL ---------------------------
__global__ __launch_bounds__(256) void loss_row_kernel(
    const float* __restrict__ logits, const int* __restrict__ tgt,
    float* __restrict__ nll)
{
    __shared__ float red[4];
    int row = blockIdx.x;
    const float* lr = logits + (size_t)row * V_DIM;
    float m = -1e30f;
    for (int i = threadIdx.x; i < V_DIM; i += 256) m = fmaxf(m, lr[i]);
#pragma unroll
    for (int o = 32; o > 0; o >>= 1) m = fmaxf(m, __shfl_xor(m, o));
    if ((threadIdx.x & 63) == 0) red[threadIdx.x >> 6] = m;
    __syncthreads();
    m = fmaxf(fmaxf(red[0], red[1]), fmaxf(red[2], red[3]));
    __syncthreads();

    float s = 0.f;
    for (int i = threadIdx.x; i < V_DIM; i += 256) s += expf(lr[i] - m);
#pragma unroll
    for (int o = 32; o > 0; o >>= 1) s += __shfl_xor(s, o);
    if ((threadIdx.x & 63) == 0) red[threadIdx.x >> 6] = s;
    __syncthreads();
    s = red[0] + red[1] + red[2] + red[3];

    if (threadIdx.x == 0) nll[row] = -(lr[tgt[row]] - m - logf(s));
}

__global__ __launch_bounds__(256) void loss_final_kernel(
    const float* __restrict__ nll, float* __restrict__ out)
{
    __shared__ float red[4];
    float s = 0.f;
    for (int i = threadIdx.x; i < NTOK; i += 256) s += nll[i];
#pragma unroll
    for (int o = 32; o > 0; o >>= 1) s += __shfl_xor(s, o);
    if ((threadIdx.x & 63) == 0) red[threadIdx.x >> 6] = s;
    __syncthreads();
    if (threadIdx.x == 0)
        out[0] = (red[0] + red[1] + red[2] + red[3]) * (1.f / NTOK);
}

// ---------------- host launch --------------------------------------------
extern "C" void kernel_launch(void* const* d_in, const int* in_sizes, int n_in,
                              void* d_out, int out_size, void* d_ws, size_t ws_size,
                              hipStream_t stream)
{
    const int*   idx     = (const int*)d_in[0];
    const int*   targets = (const int*)d_in[1];
    const float* tok_emb = (const float*)d_in[2];
    const float* pos_emb = (const float*)d_in[3];
    const float* wq      = (const float*)d_in[4];
    const float* wk      = (const float*)d_in[5];
    const float* wv      = (const float*)d_in[6];
    const float* wo      = (const float*)d_in[7];
    const float* bo      = (const float*)d_in[8];
    const float* ln1_g   = (const float*)d_in[9];
    const float* ln1_b   = (const float*)d_in[10];
    const float* ln2_g   = (const float*)d_in[11];
    const float* ln2_b   = (const float*)d_in[12];
    const float* w1      = (const float*)d_in[13];
    const float* b1      = (const float*)d_in[14];
    const float* w2      = (const float*)d_in[15];
    const float* b2      = (const float*)d_in[16];
    const float* lnf_g   = (const float*)d_in[17];
    const float* lnf_b   = (const float*)d_in[18];
    const float* lm_w    = (const float*)d_in[19];
    const float* lm_b    = (const float*)d_in[20];
    float* out = (float*)d_out;

    // ---- scratch carving ----
    // d_out (204,800,001 f32): everything here is dead before the logits GEMM.
    float* x    = out;                                   // 3,145,728 f32
    float* qkv  = out + 3145728;                         // 9,437,184 f32
    bf16*  attnb = (bf16*)(out + 12582912);              // 3,145,728 bf16
    bf16*  ffb   = (bf16*)(out + 14155776);              // 12,582,912 bf16
    bf16*  wqkvT = (bf16*)(out + 20447232);              // 6*1152*384
    bf16*  woT   = (bf16*)(out + 21774336);              // 6*384*384
    bf16*  w1T   = (bf16*)(out + 22216704);              // 6*1536*384
    bf16*  w2T   = (bf16*)(out + 23986176);              // 6*384*1536
    // d_ws: only what must survive into the logits GEMM (~25.6 MB)
    bf16*  hb   = (bf16*)d_ws;                           // 3,145,728 bf16
    bf16*  lmT  = hb + 3145728;                          // 25088*384 bf16
    float* nll  = (float*)(lmT + (size_t)V_PAD * C_DIM); // 8192 f32

    dim3 blk256(256), blk128(128), blk64(64), blkT(32, 8);

    embed_kernel<<<(NTOK * C_DIM + 255) / 256, blk256, 0, stream>>>(
        idx, tok_emb, pos_emb, x);

    // ---- weight conversion (every call; no persistent state) ----
    const long long CC = (long long)C_DIM * C_DIM;            // 147456
    const long long CF = (long long)C_DIM * FF_DIM;           // 589824
    // wq/wk/wv -> wqkvT rows [0,384)/[384,768)/[768,1152)
    {
        dim3 g(12, 12, L_LAYERS);
        tcvt_kernel<<<g, blkT, 0, stream>>>(wq, wqkvT, C_DIM, C_DIM, C_DIM,
                                            CC, (long long)QKV_LD * C_DIM, 0, C_DIM);
        tcvt_kernel<<<g, blkT, 0, stream>>>(wk, wqkvT, C_DIM, C_DIM, C_DIM,
                                            CC, (long long)QKV_LD * C_DIM, 384, C_DIM);
        tcvt_kernel<<<g, blkT, 0, stream>>>(wv, wqkvT, C_DIM, C_DIM, C_DIM,
                                            CC, (long long)QKV_LD * C_DIM, 768, C_DIM);
        tcvt_kernel<<<g, blkT, 0, stream>>>(wo, woT, C_DIM, C_DIM, C_DIM,
                                            CC, CC, 0, C_DIM);
    }
    tcvt_kernel<<<dim3(48, 12, L_LAYERS), blkT, 0, stream>>>(
        w1, w1T, C_DIM, FF_DIM, FF_DIM, CF, CF, 0, C_DIM);
    tcvt_kernel<<<dim3(12, 48, L_LAYERS), blkT, 0, stream>>>(
        w2, w2T, FF_DIM, C_DIM, C_DIM, CF, CF, 0, FF_DIM);
    tcvt_kernel<<<dim3((V_PAD + 31) / 32, 12, 1), blkT, 0, stream>>>(
        lm_w, lmT, C_DIM, V_DIM, V_PAD, 0, 0, 0, C_DIM);

    dim3 gQKV(QKV_LD / 128, NTOK / 128);   // 9 x 64
    dim3 gC(C_DIM / 128, NTOK / 128);      // 3 x 64
    dim3 gF(FF_DIM / 128, NTOK / 128);     // 12 x 64
    dim3 gV(V_PAD / 128, NTOK / 128);      // 196 x 64

    for (int l = 0; l < L_LAYERS; ++l) {
        ln_kernel<<<NTOK, blk64, 0, stream>>>(
            x, ln1_g + l * C_DIM, ln1_b + l * C_DIM, hb);
        bgemm_kernel<<<gQKV, blk256, 0, stream>>>(
            hb, wqkvT + (size_t)l * QKV_LD * C_DIM, nullptr, nullptr,
            qkv, NTOK, QKV_LD, C_DIM, 0, 0);
        attn_kernel<<<B_SZ * H_HEADS, blk128, 0, stream>>>(qkv, attnb);
        bgemm_kernel<<<gC, blk256, 0, stream>>>(
            attnb, woT + (size_t)l * CC, bo + l * C_DIM, x,
            x, NTOK, C_DIM, C_DIM, 0, 0);
        ln_kernel<<<NTOK, blk64, 0, stream>>>(
            x, ln2_g + l * C_DIM, ln2_b + l * C_DIM, hb);
        bgemm_kernel<<<gF, blk256, 0, stream>>>(
            hb, w1T + (size_t)l * CF, b1 + l * FF_DIM, nullptr,
            ffb, NTOK, FF_DIM, C_DIM, 1, 1);
        bgemm_kernel<<<gC, blk256, 0, stream>>>(
            ffb, w2T + (size_t)l * CF, b2 + l * C_DIM, x,
            x, NTOK, C_DIM, FF_DIM, 0, 0);
    }

    ln_kernel<<<NTOK, blk64, 0, stream>>>(x, lnf_g, lnf_b, hb);
    bgemm_kernel<<<gV, blk256, 0, stream>>>(
        hb, lmT, lm_b, nullptr, out, NTOK, V_DIM, C_DIM, 0, 0);

    loss_row_kernel<<<NTOK, blk256, 0, stream>>>(out, targets, nll);
    loss_final_kernel<<<1, blk256, 0, stream>>>(nll, out + (size_t)NTOK * V_DIM);
}